// Round 1
// baseline (812.230 us; speedup 1.0000x reference)
//
#include <hip/hip_runtime.h>

// ---------------------------------------------------------------------------
// PanguProMoE decoder layer, MI355X (gfx950).
// Precision strategy: pre-router chain (qkv GEMM, attention, o-proj) in
// split-f16 ("f16x2": x = hi + lo/1024, 3 MFMAs/tile) for fp32-grade router
// logits (router top-k is discrete -> needs ~1e-5 logit accuracy).
// Post-router MoE in plain f16 MFMA. All elementwise math fp32; RoPE angles
// in double (fp32 angle err ~1e-4 rad at pos 2047 would risk top-k flips).
// Required workspace: ~142.7 MB (phase-overlapped arena, see kernel_launch).
// ---------------------------------------------------------------------------

typedef _Float16 half_t;
typedef _Float16 half8 __attribute__((ext_vector_type(8)));
typedef float    f32x4 __attribute__((ext_vector_type(4)));
typedef float    floatx4 __attribute__((ext_vector_type(4)));

#define T_TOK 2048
#define HIDN  2048
#define NH    16
#define NKVH  4
#define HD    128
#define QKV_N 3072
#define NEXP  8

#define MFMA16(a,b,c) __builtin_amdgcn_mfma_f32_16x16x32_f16(a,b,c,0,0,0)

// ---------------------------------------------------------------------------
// rmsnorm over HIDN cols, write split f16 (lo optional)
// ---------------------------------------------------------------------------
__global__ __launch_bounds__(256)
void rmsnorm_split_k(const float* __restrict__ x, const float* __restrict__ w,
                     half_t* __restrict__ hi, half_t* __restrict__ lo)
{
    const int row = blockIdx.x, tid = threadIdx.x;
    const float* xr = x + (size_t)row * HIDN;
    floatx4 v0 = *(const floatx4*)(xr + tid * 8);
    floatx4 v1 = *(const floatx4*)(xr + tid * 8 + 4);
    float ss = v0[0]*v0[0] + v0[1]*v0[1] + v0[2]*v0[2] + v0[3]*v0[3]
             + v1[0]*v1[0] + v1[1]*v1[1] + v1[2]*v1[2] + v1[3]*v1[3];
    for (int o = 32; o; o >>= 1) ss += __shfl_down(ss, o);
    __shared__ float red[4];
    if ((tid & 63) == 0) red[tid >> 6] = ss;
    __syncthreads();
    ss = red[0] + red[1] + red[2] + red[3];
    float rs = rsqrtf(ss * (1.0f / HIDN) + 1e-6f);
    floatx4 w0 = *(const floatx4*)(w + tid * 8);
    floatx4 w1 = *(const floatx4*)(w + tid * 8 + 4);
    float vv[8] = { v0[0]*w0[0], v0[1]*w0[1], v0[2]*w0[2], v0[3]*w0[3],
                    v1[0]*w1[0], v1[1]*w1[1], v1[2]*w1[2], v1[3]*w1[3] };
    half8 hv, lv;
#pragma unroll
    for (int j = 0; j < 8; ++j) {
        float o = vv[j] * rs;
        half_t h = (half_t)o;
        hv[j] = h;
        lv[j] = (half_t)((o - (float)h) * 1024.0f);
    }
    *(half8*)(hi + (size_t)row * HIDN + tid * 8) = hv;
    if (lo) *(half8*)(lo + (size_t)row * HIDN + tid * 8) = lv;
}

// ---------------------------------------------------------------------------
// transpose + fp32 -> split f16 convert: dst[n][k] = src[k][n]
// ---------------------------------------------------------------------------
__global__ __launch_bounds__(256)
void transpose_split(const float* __restrict__ src,
                     half_t* __restrict__ dh, half_t* __restrict__ dl,
                     int K, int N, int sstride, int dstride)
{
    __shared__ float tile[32][33];
    const int n0 = blockIdx.x * 32, k0 = blockIdx.y * 32;
    const int tx = threadIdx.x & 31, ty = threadIdx.x >> 5;
#pragma unroll
    for (int i = 0; i < 4; ++i)
        tile[ty + i * 8][tx] = src[(size_t)(k0 + ty + i * 8) * sstride + n0 + tx];
    __syncthreads();
#pragma unroll
    for (int i = 0; i < 4; ++i) {
        int n = ty + i * 8;
        float v = tile[tx][n];
        half_t h = (half_t)v;
        size_t o = (size_t)(n0 + n) * dstride + k0 + tx;
        dh[o] = h;
        if (dl) dl[o] = (half_t)((v - (float)h) * 1024.0f);
    }
}

// ---------------------------------------------------------------------------
// GEMM: C[M][N] = A[M][K] @ Bt[N][K]^T (+bias)(+res). f16 inputs, fp32 acc.
// SPLIT: inputs are (hi, lo*1024) pairs; 3 MFMAs/tile, cross acc scaled 2^-10.
// 128x128 tile, BK=32, 4 waves (each 64x64 = 4x4 16x16 frags). LDS rows
// padded to 40 halfs (80B) -> 2-way max bank aliasing on ds_read_b128.
// ---------------------------------------------------------------------------
template<bool SPLIT>
__global__ __launch_bounds__(256, 2)
void gemm_f16(const half_t* __restrict__ Ah, const half_t* __restrict__ Al,
              const half_t* __restrict__ Bth, const half_t* __restrict__ Btl,
              const float* __restrict__ bias, const float* __restrict__ res,
              float* __restrict__ Cf, half_t* __restrict__ Ch,
              int M, int N, int K)
{
    constexpr int NBUF = SPLIT ? 2 : 1;
    constexpr int PK = 40;
    __shared__ half_t As[NBUF][128 * PK];
    __shared__ half_t Bs[NBUF][128 * PK];
    const int tid = threadIdx.x, lane = tid & 63, wid = tid >> 6;
    const int l15 = lane & 15, l4 = lane >> 4;
    const int row0 = blockIdx.y * 128, col0 = blockIdx.x * 128;
    const int wr = (wid >> 1) * 64, wc = (wid & 1) * 64;
    f32x4 accM[4][4] = {}, accC[4][4] = {};
    const int sr = tid >> 2, sg = tid & 3;

    for (int k0 = 0; k0 < K; k0 += 32) {
        __syncthreads();
#pragma unroll
        for (int it = 0; it < 2; ++it) {
            int r = sr + it * 64;
            size_t ga = (size_t)(row0 + r) * K + k0 + sg * 8;
            size_t gb = (size_t)(col0 + r) * K + k0 + sg * 8;
            int lo_ = r * PK + sg * 8;
            *(uint4*)&As[0][lo_] = *(const uint4*)(Ah + ga);
            *(uint4*)&Bs[0][lo_] = *(const uint4*)(Bth + gb);
            if constexpr (SPLIT) {
                *(uint4*)&As[1][lo_] = *(const uint4*)(Al + ga);
                *(uint4*)&Bs[1][lo_] = *(const uint4*)(Btl + gb);
            }
        }
        __syncthreads();
        half8 ah[4], al[4], bh[4], bl[4];
#pragma unroll
        for (int m = 0; m < 4; ++m) {
            int off = (wr + m * 16 + l15) * PK + l4 * 8;
            ah[m] = *(const half8*)&As[0][off];
            if constexpr (SPLIT) al[m] = *(const half8*)&As[1][off];
        }
#pragma unroll
        for (int n = 0; n < 4; ++n) {
            int off = (wc + n * 16 + l15) * PK + l4 * 8;
            bh[n] = *(const half8*)&Bs[0][off];
            if constexpr (SPLIT) bl[n] = *(const half8*)&Bs[1][off];
        }
#pragma unroll
        for (int m = 0; m < 4; ++m)
#pragma unroll
            for (int n = 0; n < 4; ++n) {
                accM[m][n] = MFMA16(ah[m], bh[n], accM[m][n]);
                if constexpr (SPLIT) {
                    accC[m][n] = MFMA16(ah[m], bl[n], accC[m][n]);
                    accC[m][n] = MFMA16(al[m], bh[n], accC[m][n]);
                }
            }
    }
#pragma unroll
    for (int m = 0; m < 4; ++m) {
#pragma unroll
        for (int n = 0; n < 4; ++n) {
            int gr0 = row0 + wr + m * 16 + l4 * 4;
            int gc  = col0 + wc + n * 16 + l15;
            float b = bias ? bias[gc] : 0.0f;
#pragma unroll
            for (int i = 0; i < 4; ++i) {
                float v = accM[m][n][i];
                if constexpr (SPLIT) v += accC[m][n][i] * (1.0f / 1024.0f);
                v += b;
                size_t idx = (size_t)(gr0 + i) * N + gc;
                if (res) v += res[idx];
                if (Cf) Cf[idx] = v;
                if (Ch) Ch[idx] = (half_t)v;
            }
        }
    }
}

// ---------------------------------------------------------------------------
// qkv post-processing: k-rmsnorm, RoPE on q/k (last 64 dims, half=32),
// split-f16 outputs. vT stored [kvh][d][t] for transpose-free PV staging.
// ---------------------------------------------------------------------------
__global__ __launch_bounds__(256)
void qkv_prep(const float* __restrict__ qkv, const int* __restrict__ pos,
              const float* __restrict__ klnw,
              half_t* __restrict__ qh, half_t* __restrict__ ql,
              half_t* __restrict__ kh, half_t* __restrict__ kl,
              half_t* __restrict__ vth, half_t* __restrict__ vtl)
{
    const int t = blockIdx.x, tid = threadIdx.x, lane = tid & 63, wid = tid >> 6;
    const float* row = qkv + (size_t)t * QKV_N;
    __shared__ float cs[32], sn[32];
    if (tid < 32) {
        // inv_freq = 10000^(-j/32); double + exact 2pi reduction (pos<=2047)
        double freq = exp((double)tid * -0.28782313662425572);  // -ln(1e4)/32
        double ang = (double)pos[t] * freq;
        const double twopi = 6.283185307179586476925286766559;
        ang -= twopi * floor(ang * (1.0 / twopi));
        float a = (float)ang;
        cs[tid] = cosf(a);
        sn[tid] = sinf(a);
    }
    __syncthreads();

    // ---- Q: thread -> (head = tid>>4, d0 = (tid&15)*8)
    {
        const int hh = tid >> 4, d0 = (tid & 15) * 8;
        const float* qrow = row + hh * HD;
        float outv[8];
        if (d0 < 64) {
#pragma unroll
            for (int j = 0; j < 8; ++j) outv[j] = qrow[d0 + j];
        } else if (d0 < 96) {
            int j0 = d0 - 64;
#pragma unroll
            for (int j = 0; j < 8; ++j) {
                int jj = j0 + j;
                outv[j] = qrow[64 + jj] * cs[jj] - qrow[96 + jj] * sn[jj];
            }
        } else {
            int j0 = d0 - 96;
#pragma unroll
            for (int j = 0; j < 8; ++j) {
                int jj = j0 + j;
                outv[j] = qrow[64 + jj] * sn[jj] + qrow[96 + jj] * cs[jj];
            }
        }
        half8 hv, lv;
#pragma unroll
        for (int j = 0; j < 8; ++j) {
            half_t h = (half_t)outv[j];
            hv[j] = h;
            lv[j] = (half_t)((outv[j] - (float)h) * 1024.0f);
        }
        size_t base = (size_t)t * (NH * HD) + hh * HD + d0;
        *(half8*)(qh + base) = hv;
        *(half8*)(ql + base) = lv;
    }

    // ---- K: wave wid handles kv-head wid; rmsnorm(128) then rope
    {
        const float* krow = row + NH * HD + wid * HD;
        float a0 = krow[lane], a1 = krow[64 + lane];
        float ss = a0 * a0 + a1 * a1;
        for (int o = 32; o; o >>= 1) ss += __shfl_down(ss, o);
        ss = __shfl(ss, 0);
        float rs = rsqrtf(ss * (1.0f / HD) + 1e-6f);
        float n0 = a0 * rs * klnw[lane];
        float n1 = a1 * rs * klnw[64 + lane];
        float other = __shfl_xor(n1, 32);
        int j = lane & 31;
        float o1 = (lane < 32) ? (n1 * cs[j] - other * sn[j])
                               : (other * sn[j] + n1 * cs[j]);
        size_t base = (size_t)t * (NKVH * HD) + wid * HD;
        half_t h;
        h = (half_t)n0; kh[base + lane] = h;
        kl[base + lane] = (half_t)((n0 - (float)h) * 1024.0f);
        h = (half_t)o1; kh[base + 64 + lane] = h;
        kl[base + 64 + lane] = (half_t)((o1 - (float)h) * 1024.0f);
    }

    // ---- V: vT[kvh*128+d][t]
    {
#pragma unroll
        for (int it = 0; it < 2; ++it) {
            int e = tid + it * 256;
            float v = row[NH * HD + NKVH * HD + e];
            size_t o = (size_t)e * T_TOK + t;
            half_t h = (half_t)v;
            vth[o] = h;
            vtl[o] = (half_t)((v - (float)h) * 1024.0f);
        }
    }
}

// ---------------------------------------------------------------------------
// Flash attention, causal GQA (16 heads, 4 kv heads), split-f16 MFMA.
// Block = (q-block of 64 rows, head); 4 waves x 16 q-rows; KV tiles of 32.
// ---------------------------------------------------------------------------
__global__ __launch_bounds__(256, 2)
void attn_kernel(const half_t* __restrict__ qh, const half_t* __restrict__ ql,
                 const half_t* __restrict__ kh, const half_t* __restrict__ kl,
                 const half_t* __restrict__ vth, const half_t* __restrict__ vtl,
                 half_t* __restrict__ oh, half_t* __restrict__ ol)
{
    const int qblk = blockIdx.x, h = blockIdx.y;
    const int kvh = h >> 2;
    const int tid = threadIdx.x, lane = tid & 63, wid = tid >> 6;
    const int q0 = qblk * 64 + wid * 16;
    const int l15 = lane & 15, l4 = lane >> 4;

    __shared__ half_t Ksh[32][136], Ksl[32][136];  // padded: 2-way banks max
    __shared__ half_t Vsh[128][40], Vsl[128][40];
    __shared__ half_t Ph[4][16][40], Pl[4][16][40];

    half8 qfh[4], qfl[4];
    {
        const size_t qb = (size_t)(q0 + l15) * (NH * HD) + h * HD + l4 * 8;
#pragma unroll
        for (int c = 0; c < 4; ++c) {
            qfh[c] = *(const half8*)(qh + qb + c * 32);
            qfl[c] = *(const half8*)(ql + qb + c * 32);
        }
    }

    f32x4 om[8] = {}, oc[8] = {};
    float mrow[4] = { -1e30f, -1e30f, -1e30f, -1e30f };
    float lrow[4] = {};

    const int kvend = qblk * 64 + 64;
    for (int kv0 = 0; kv0 < kvend; kv0 += 32) {
#pragma unroll
        for (int it = 0; it < 2; ++it) {          // stage K (32x128, hi/lo)
            int s = tid + it * 256;
            int r = s >> 4, cg = s & 15;
            size_t src = (size_t)(kv0 + r) * (NKVH * HD) + kvh * HD + cg * 8;
            *(uint4*)&Ksh[r][cg * 8] = *(const uint4*)(kh + src);
            *(uint4*)&Ksl[r][cg * 8] = *(const uint4*)(kl + src);
        }
#pragma unroll
        for (int it = 0; it < 2; ++it) {          // stage V^T (128x32, hi/lo)
            int s = tid + it * 256;
            int d = s >> 2, cg = s & 3;
            size_t src = (size_t)(kvh * HD + d) * T_TOK + kv0 + cg * 8;
            *(uint4*)&Vsh[d][cg * 8] = *(const uint4*)(vth + src);
            *(uint4*)&Vsl[d][cg * 8] = *(const uint4*)(vtl + src);
        }
        __syncthreads();

        f32x4 sf[2];
#pragma unroll
        for (int t2 = 0; t2 < 2; ++t2) {          // S = Q K^T
            f32x4 s = {}, sc = {};
#pragma unroll
            for (int c = 0; c < 4; ++c) {
                half8 bh = *(const half8*)&Ksh[t2 * 16 + l15][c * 32 + l4 * 8];
                half8 bl = *(const half8*)&Ksl[t2 * 16 + l15][c * 32 + l4 * 8];
                s  = MFMA16(qfh[c], bh, s);
                sc = MFMA16(qfh[c], bl, sc);
                sc = MFMA16(qfl[c], bh, sc);
            }
            sf[t2] = s + sc * (1.0f / 1024.0f);
        }

        const float scale = 0.088388347648318447f;   // 128^-0.5
#pragma unroll
        for (int i = 0; i < 4; ++i) {
            const int qg = q0 + l4 * 4 + i;
#pragma unroll
            for (int t2 = 0; t2 < 2; ++t2) {
                int kvg = kv0 + t2 * 16 + l15;
                float sv = sf[t2][i] * scale;
                sf[t2][i] = (kvg > qg) ? -1e30f : sv;
            }
            float mx = fmaxf(sf[0][i], sf[1][i]);
#pragma unroll
            for (int o = 1; o < 16; o <<= 1) mx = fmaxf(mx, __shfl_xor(mx, o));
            float mnew = fmaxf(mrow[i], mx);
            float resc = expf(mrow[i] - mnew);
            float p0 = expf(sf[0][i] - mnew);
            float p1 = expf(sf[1][i] - mnew);
            lrow[i] = lrow[i] * resc + p0 + p1;
            mrow[i] = mnew;
#pragma unroll
            for (int c8 = 0; c8 < 8; ++c8) { om[c8][i] *= resc; oc[c8][i] *= resc; }
            half_t hh;
            hh = (half_t)p0;
            Ph[wid][l4 * 4 + i][l15] = hh;
            Pl[wid][l4 * 4 + i][l15] = (half_t)((p0 - (float)hh) * 1024.0f);
            hh = (half_t)p1;
            Ph[wid][l4 * 4 + i][16 + l15] = hh;
            Pl[wid][l4 * 4 + i][16 + l15] = (half_t)((p1 - (float)hh) * 1024.0f);
        }

        half8 pah = *(const half8*)&Ph[wid][l15][l4 * 8];
        half8 pal = *(const half8*)&Pl[wid][l15][l4 * 8];
#pragma unroll
        for (int c8 = 0; c8 < 8; ++c8) {          // O += P V
            half8 vh = *(const half8*)&Vsh[c8 * 16 + l15][l4 * 8];
            half8 vl = *(const half8*)&Vsl[c8 * 16 + l15][l4 * 8];
            om[c8] = MFMA16(pah, vh, om[c8]);
            oc[c8] = MFMA16(pah, vl, oc[c8]);
            oc[c8] = MFMA16(pal, vh, oc[c8]);
        }
        __syncthreads();
    }

#pragma unroll
    for (int i = 0; i < 4; ++i)
#pragma unroll
        for (int o = 1; o < 16; o <<= 1) lrow[i] += __shfl_xor(lrow[i], o);

#pragma unroll
    for (int c8 = 0; c8 < 8; ++c8) {
#pragma unroll
        for (int i = 0; i < 4; ++i) {
            float v = (om[c8][i] + oc[c8][i] * (1.0f / 1024.0f)) / lrow[i];
            size_t idx = (size_t)(q0 + l4 * 4 + i) * (NH * HD) + h * HD + c8 * 16 + l15;
            half_t hh = (half_t)v;
            oh[idx] = hh;
            ol[idx] = (half_t)((v - (float)hh) * 1024.0f);
        }
    }
}

// ---------------------------------------------------------------------------
// Router: h2 = rmsnorm(x2, ln2w); logits = h2 @ rw; top-2 normalized weights.
// fp32 throughout (discrete decision must match the fp-accurate reference).
// ---------------------------------------------------------------------------
__global__ __launch_bounds__(256)
void router_kernel(const float* __restrict__ x2, const float* __restrict__ ln2w,
                   const float* __restrict__ rw, float* __restrict__ combine)
{
    const int t = blockIdx.x, tid = threadIdx.x;
    const float* xr = x2 + (size_t)t * HIDN;
    float vals[8];
    float ss = 0.0f;
#pragma unroll
    for (int i = 0; i < 8; ++i) {
        vals[i] = xr[tid + i * 256];
        ss += vals[i] * vals[i];
    }
    for (int o = 32; o; o >>= 1) ss += __shfl_down(ss, o);
    __shared__ float red[4];
    if ((tid & 63) == 0) red[tid >> 6] = ss;
    __syncthreads();
    ss = red[0] + red[1] + red[2] + red[3];
    float rs = rsqrtf(ss * (1.0f / HIDN) + 1e-6f);

    float acc[NEXP] = {};
#pragma unroll
    for (int i = 0; i < 8; ++i) {
        int c = tid + i * 256;
        float hv = vals[i] * rs * ln2w[c];
        const float* wr = rw + (size_t)c * NEXP;
#pragma unroll
        for (int e = 0; e < NEXP; ++e) acc[e] += hv * wr[e];
    }
#pragma unroll
    for (int e = 0; e < NEXP; ++e)
        for (int o = 32; o; o >>= 1) acc[e] += __shfl_down(acc[e], o);
    __shared__ float red8[4][NEXP];
    if ((tid & 63) == 0)
#pragma unroll
        for (int e = 0; e < NEXP; ++e) red8[tid >> 6][e] = acc[e];
    __syncthreads();
    if (tid == 0) {
        float lg[NEXP];
#pragma unroll
        for (int e = 0; e < NEXP; ++e)
            lg[e] = red8[0][e] + red8[1][e] + red8[2][e] + red8[3][e];
        int i1 = 0;
        for (int e = 1; e < NEXP; ++e) if (lg[e] > lg[i1]) i1 = e;
        int i2 = (i1 == 0) ? 1 : 0;
        for (int e = 0; e < NEXP; ++e) if (e != i1 && lg[e] > lg[i2]) i2 = e;
        float mx = lg[i1];
        float p1 = expf(lg[i1] - mx), p2 = expf(lg[i2] - mx);
        float inv = 1.0f / (p1 + p2);
        float* cr = combine + (size_t)t * NEXP;
#pragma unroll
        for (int e = 0; e < NEXP; ++e) cr[e] = 0.0f;
        cr[i1] = p1 * inv;
        cr[i2] = p2 * inv;
    }
}

// ---------------------------------------------------------------------------
// MoE activation: Abig[t][n] = scale * silu(G[t][n]) * U[t][n]
// GU layout [T][10240]: cols 0..5119 gate, 5120..10239 up.
// scale = 1 for shared (n<1024) else combine[t][(n-1024)/512].
// ---------------------------------------------------------------------------
__global__ __launch_bounds__(256)
void moe_act(const half_t* __restrict__ GU, const float* __restrict__ comb,
             half_t* __restrict__ Abig)
{
    int idx = blockIdx.x * 256 + threadIdx.x;   // T*640 threads, 8 elems each
    int t = idx / 640, c8 = idx % 640;
    int n = c8 * 8;
    half8 g8 = *(const half8*)(GU + (size_t)t * 10240 + n);
    half8 u8 = *(const half8*)(GU + (size_t)t * 10240 + 5120 + n);
    float sc = (n < 1024) ? 1.0f : comb[(size_t)t * NEXP + ((n - 1024) >> 9)];
    half8 o8;
#pragma unroll
    for (int j = 0; j < 8; ++j) {
        float g = (float)g8[j], u = (float)u8[j];
        float s = g / (1.0f + expf(-g));
        o8[j] = (half_t)(s * u * sc);
    }
    *(half8*)(Abig + (size_t)t * 5120 + n) = o8;
}

// ---------------------------------------------------------------------------
extern "C" void kernel_launch(void* const* d_in, const int* in_sizes, int n_in,
                              void* d_out, int out_size, void* d_ws, size_t ws_size,
                              hipStream_t stream)
{
    (void)in_sizes; (void)n_in; (void)out_size; (void)ws_size;
    const float* x    = (const float*)d_in[0];
    const int*   pos  = (const int*)  d_in[1];
    const float* ln1w = (const float*)d_in[2];
    const float* qkvw = (const float*)d_in[3];
    const float* qkvb = (const float*)d_in[4];
    const float* klnw = (const float*)d_in[5];
    const float* ow   = (const float*)d_in[6];
    const float* ln2w = (const float*)d_in[7];
    const float* rw   = (const float*)d_in[8];
    const float* w1   = (const float*)d_in[9];
    const float* w2   = (const float*)d_in[10];
    const float* w3   = (const float*)d_in[11];
    const float* sw1  = (const float*)d_in[12];
    const float* sw2  = (const float*)d_in[13];
    const float* sw3  = (const float*)d_in[14];
    float* out = (float*)d_out;

    // ---- workspace arena (phase-overlapped; total 142,671,872 B) ----
    char* ws = (char*)d_ws;
    const size_t AB = 16842752;   // after x2 + combine
    float*  x2      = (float*)(ws);
    float*  combine = (float*)(ws + 16777216);
    half_t* h_hi    = (half_t*)(ws + AB);
    half_t* h_lo    = (half_t*)(ws + AB + 8388608);
    half_t* qkvwt_h = (half_t*)(ws + AB + 16777216);
    half_t* qkvwt_l = (half_t*)(ws + AB + 29360128);
    float*  qkv     = (float*)(ws + AB + 41943040);
    half_t* q_h     = (half_t*)(ws + AB + 67108864);
    half_t* q_l     = (half_t*)(ws + AB + 75497472);
    half_t* k_h     = (half_t*)(ws + AB + 83886080);
    half_t* k_l     = (half_t*)(ws + AB + 85983232);
    half_t* vt_h    = (half_t*)(ws + AB + 88080384);
    half_t* vt_l    = (half_t*)(ws + AB + 90177536);
    half_t* attn_h  = (half_t*)(ws + AB);             // reuse h_hi
    half_t* attn_l  = (half_t*)(ws + AB + 8388608);   // reuse h_lo
    half_t* owt_h   = (half_t*)(ws + AB + 16777216);  // reuse qkvwt
    half_t* owt_l   = (half_t*)(ws + AB + 25165824);
    half_t* h2      = (half_t*)(ws + AB + 33554432);
    half_t* W13t    = (half_t*)(ws + AB + 41943040);  // reuse qkv + q (dead)
    half_t* GU      = (half_t*)(ws + AB + 83886080);  // reuse k/vt (dead)
    half_t* Abig    = (half_t*)(ws + AB);             // reuse attn (dead)
    half_t* W2t     = (half_t*)(ws + AB + 41943040);  // reuse W13t (dead)

    dim3 b256(256);

    // 1. h = rmsnorm(x, ln1_w) split
    rmsnorm_split_k<<<T_TOK, b256, 0, stream>>>(x, ln1w, h_hi, h_lo);
    // 2. qkv_w -> transposed split f16
    transpose_split<<<dim3(QKV_N / 32, HIDN / 32), b256, 0, stream>>>(
        qkvw, qkvwt_h, qkvwt_l, HIDN, QKV_N, QKV_N, HIDN);
    // 3. qkv = h @ qkv_w + b   (split path)
    gemm_f16<true><<<dim3(QKV_N / 128, T_TOK / 128), b256, 0, stream>>>(
        h_hi, h_lo, qkvwt_h, qkvwt_l, qkvb, nullptr, qkv, nullptr,
        T_TOK, QKV_N, HIDN);
    // 4. k-rmsnorm + rope + split
    qkv_prep<<<T_TOK, b256, 0, stream>>>(qkv, pos, klnw,
                                         q_h, q_l, k_h, k_l, vt_h, vt_l);
    // 5. o_w transpose (into region freed by qkvwt)
    transpose_split<<<dim3(HIDN / 32, HIDN / 32), b256, 0, stream>>>(
        ow, owt_h, owt_l, HIDN, HIDN, HIDN, HIDN);
    // 6. attention
    attn_kernel<<<dim3(T_TOK / 64, NH), b256, 0, stream>>>(
        q_h, q_l, k_h, k_l, vt_h, vt_l, attn_h, attn_l);
    // 7. x2 = x + attn @ o_w   (split path)
    gemm_f16<true><<<dim3(HIDN / 128, T_TOK / 128), b256, 0, stream>>>(
        attn_h, attn_l, owt_h, owt_l, nullptr, x, x2, nullptr,
        T_TOK, HIDN, HIDN);
    // 8. router -> combine weights
    router_kernel<<<T_TOK, b256, 0, stream>>>(x2, ln2w, rw, combine);
    // 9. h2 = rmsnorm(x2, ln2_w), single f16
    rmsnorm_split_k<<<T_TOK, b256, 0, stream>>>(x2, ln2w, h2, nullptr);
    // 10. W13t: [sw1 | w1[e]... | sw3 | w3[e]...] transposed (after attn:
    //     overwrites dead qkv/q regions)
    transpose_split<<<dim3(1024 / 32, HIDN / 32), b256, 0, stream>>>(
        sw1, W13t, nullptr, HIDN, 1024, 1024, HIDN);
    for (int e = 0; e < NEXP; ++e)
        transpose_split<<<dim3(512 / 32, HIDN / 32), b256, 0, stream>>>(
            w1 + (size_t)e * HIDN * 512, W13t + (size_t)(1024 + 512 * e) * HIDN,
            nullptr, HIDN, 512, 512, HIDN);
    transpose_split<<<dim3(1024 / 32, HIDN / 32), b256, 0, stream>>>(
        sw3, W13t + (size_t)5120 * HIDN, nullptr, HIDN, 1024, 1024, HIDN);
    for (int e = 0; e < NEXP; ++e)
        transpose_split<<<dim3(512 / 32, HIDN / 32), b256, 0, stream>>>(
            w3 + (size_t)e * HIDN * 512, W13t + (size_t)(6144 + 512 * e) * HIDN,
            nullptr, HIDN, 512, 512, HIDN);
    // 11. GU = h2 @ [W1|W3]  (single f16, f16 out)
    gemm_f16<false><<<dim3(10240 / 128, T_TOK / 128), b256, 0, stream>>>(
        h2, nullptr, W13t, nullptr, nullptr, nullptr, nullptr, GU,
        T_TOK, 10240, HIDN);
    // 12. W2t (overwrites dead W13t region)
    transpose_split<<<dim3(HIDN / 32, 1024 / 32), b256, 0, stream>>>(
        sw2, W2t, nullptr, 1024, HIDN, HIDN, 5120);
    for (int e = 0; e < NEXP; ++e)
        transpose_split<<<dim3(HIDN / 32, 512 / 32), b256, 0, stream>>>(
            w2 + (size_t)e * 512 * HIDN, W2t + 1024 + 512 * e,
            nullptr, 512, HIDN, HIDN, 5120);
    // 13. Abig = combine-scaled silu(G)*U
    moe_act<<<(T_TOK * 640) / 256, b256, 0, stream>>>(GU, combine, Abig);
    // 14. out = x2 + Abig @ W2cat
    gemm_f16<false><<<dim3(HIDN / 128, T_TOK / 128), b256, 0, stream>>>(
        Abig, nullptr, W2t, nullptr, nullptr, x2, out, nullptr,
        T_TOK, HIDN, 5120);
}